// Round 1
// baseline (64.850 us; speedup 1.0000x reference)
//
#include <hip/hip_runtime.h>
#include <hip/hip_bf16.h>

#define BATCH 16
#define FRAMES 8192
#define TLEN 512
#define EDIM 256

typedef __attribute__((ext_vector_type(8))) short short8;
typedef __attribute__((ext_vector_type(4))) float f32x4;

__device__ __forceinline__ unsigned short f2bf(float f) {
    unsigned u = __float_as_uint(f);
    u = (u + 0x7fffu + ((u >> 16) & 1u)) >> 16;
    return (unsigned short)u;
}

// ---------------------------------------------------------------------------
// K1a: parallel guess of aligner indices + exact verification.
// guess[j] = min(#run-starts in ap[0..j], TLEN-1). One block per batch.
// Verify recurrence ind_j = (ap[j]==tp[ind_{j-1}]) ? ind : min(ind+1,TLEN-1).
// ---------------------------------------------------------------------------
__global__ __launch_bounds__(1024) void k_guess(const int* __restrict__ ap,
                                                const int* __restrict__ tp,
                                                int* __restrict__ inds,
                                                int* __restrict__ flags) {
    int b = blockIdx.x;
    int tid = threadIdx.x;
    __shared__ int sums[1024];
    __shared__ int tps[TLEN];
    __shared__ int blockOk;
    const int* apb = ap + b * FRAMES;
    if (tid < TLEN) tps[tid] = tp[b * TLEN + tid];
    if (tid == 0) blockOk = 1;
    int j0 = tid * 8;
    int4 v0 = ((const int4*)apb)[tid * 2];
    int4 v1 = ((const int4*)apb)[tid * 2 + 1];
    int prev = (tid == 0) ? v0.x : apb[j0 - 1];
    int a[8] = {v0.x, v0.y, v0.z, v0.w, v1.x, v1.y, v1.z, v1.w};
    int p[8];
    int c = 0;
    int pr = prev;
#pragma unroll
    for (int k = 0; k < 8; ++k) {
        int rs = ((j0 + k) > 0) && (a[k] != pr);
        c += rs;
        p[k] = c;
        pr = a[k];
    }
    sums[tid] = c;
    __syncthreads();
    for (int s = 1; s < 1024; s <<= 1) {
        int add = (tid >= s) ? sums[tid - s] : 0;
        __syncthreads();
        sums[tid] += add;
        __syncthreads();
    }
    int incl = sums[tid];
    int excl = incl - c;
    int g[8];
#pragma unroll
    for (int k = 0; k < 8; ++k) g[k] = min(excl + p[k], TLEN - 1);
    int4 w0, w1;
    w0.x = g[0]; w0.y = g[1]; w0.z = g[2]; w0.w = g[3];
    w1.x = g[4]; w1.y = g[5]; w1.z = g[6]; w1.w = g[7];
    ((int4*)(inds + b * FRAMES))[tid * 2] = w0;
    ((int4*)(inds + b * FRAMES))[tid * 2 + 1] = w1;
    // verify against exact recurrence
    int ok = 1;
    int gp = min(excl, TLEN - 1);  // = guess[j0-1] for j0>0
#pragma unroll
    for (int k = 0; k < 8; ++k) {
        int j = j0 + k;
        int e;
        if (j == 0) e = 0;
        else e = (a[k] == tps[gp]) ? gp : min(gp + 1, TLEN - 1);
        ok &= (g[k] == e);
        gp = g[k];
    }
    if (!ok) atomicAnd(&blockOk, 0);
    __syncthreads();
    if (tid == 0) flags[b] = blockOk;
}

// ---------------------------------------------------------------------------
// K1b: exact serial fallback (exits immediately when guess verified).
// ---------------------------------------------------------------------------
__global__ void k_fallback(const int* __restrict__ ap, const int* __restrict__ tp,
                           int* __restrict__ inds, const int* __restrict__ flags) {
    int b = blockIdx.x;
    if (flags[b]) return;
    __shared__ int tps[TLEN];
    for (int t = threadIdx.x; t < TLEN; t += blockDim.x) tps[t] = tp[b * TLEN + t];
    __syncthreads();
    if (threadIdx.x != 0) return;
    int ind = 0;
    int cur = tps[0];
    int* ob = inds + b * FRAMES;
    const int* apb = ap + b * FRAMES;
    ob[0] = 0;
    for (int j = 1; j < FRAMES; ++j) {
        int aj = apb[j];
        if (aj != cur) {
            if (ind < TLEN - 1) { ind++; cur = tps[ind]; }
        }
        ob[j] = ind;
    }
}

// ---------------------------------------------------------------------------
// K2: merged bf16-MFMA GEMM.
//   blocks 0..127  : G[row][d] = enc[row][d] + sum_e enc[row][e]*W[d][e]
//   blocks 128..255: Q[f][d]   = sum_e PE[f][e]*W[d][e] + pos_b[d] + pit_b[d]
// 64 rows/block, 4 waves, wave handles 16 rows x 256 cols (16 MFMA tiles).
// A/B frags: lane holds 8 contiguous bf16 -> single 16B LDS read each.
// ---------------------------------------------------------------------------
__global__ __launch_bounds__(256) void k_gemm(const float* __restrict__ X,
                                              const float* __restrict__ W,
                                              const float* __restrict__ pos_b,
                                              const float* __restrict__ pit_b,
                                              float* __restrict__ G,
                                              float* __restrict__ Q) {
    __shared__ unsigned short Xs[64 * 32];
    __shared__ unsigned short Ws[256 * 32];
    int bid = blockIdx.x;
    int qmode = (bid >= 128);
    int row0 = (qmode ? bid - 128 : bid) * 64;
    int tid = threadIdx.x;
    int lane = tid & 63, wv = tid >> 6;
    int c = lane & 15, gq = lane >> 4;
    f32x4 acc[16];
#pragma unroll
    for (int i = 0; i < 16; ++i) acc[i] = (f32x4){0.f, 0.f, 0.f, 0.f};

    const float kPE = -0.03597789207803197f;  // -ln(10000)/256

    for (int ks = 0; ks < 8; ++ks) {
        int k0 = ks * 32;
        __syncthreads();
        {   // stage X tile [64 rows][32 k] as bf16
            int r = tid >> 2, part = tid & 3;
            short8 ov;
            if (!qmode) {
                f32x4 u0 = *(const f32x4*)(X + (row0 + r) * EDIM + k0 + part * 8);
                f32x4 u1 = *(const f32x4*)(X + (row0 + r) * EDIM + k0 + part * 8 + 4);
                ov[0] = (short)f2bf(u0[0]); ov[1] = (short)f2bf(u0[1]);
                ov[2] = (short)f2bf(u0[2]); ov[3] = (short)f2bf(u0[3]);
                ov[4] = (short)f2bf(u1[0]); ov[5] = (short)f2bf(u1[1]);
                ov[6] = (short)f2bf(u1[2]); ov[7] = (short)f2bf(u1[3]);
            } else {
                int f = row0 + r;
                int e0 = k0 + part * 8;
#pragma unroll
                for (int jj = 0; jj < 4; ++jj) {
                    int i2 = (e0 >> 1) + jj;
                    float dv = expf((float)(2 * i2) * kPE);
                    float arg = (float)f * dv;
                    ov[2 * jj] = (short)f2bf(sinf(arg));
                    ov[2 * jj + 1] = (short)f2bf(cosf(arg));
                }
            }
            *((short8*)&Xs[r * 32 + part * 8]) = ov;
        }
        {   // stage W tile [256 d][32 k] as bf16 (coalesced 8-lane row chunks)
            int dg = tid >> 3, kq = tid & 7;
#pragma unroll
            for (int m = 0; m < 8; ++m) {
                int d = dg + 32 * m;
                f32x4 u = *(const f32x4*)(W + d * EDIM + k0 + kq * 4);
                unsigned long long pk = (unsigned long long)f2bf(u[0]) |
                                        ((unsigned long long)f2bf(u[1]) << 16) |
                                        ((unsigned long long)f2bf(u[2]) << 32) |
                                        ((unsigned long long)f2bf(u[3]) << 48);
                *((unsigned long long*)&Ws[d * 32 + kq * 4]) = pk;
            }
        }
        __syncthreads();
        short8 afrag = *((const short8*)&Xs[(wv * 16 + c) * 32 + gq * 8]);
#pragma unroll
        for (int tc = 0; tc < 16; ++tc) {
            short8 bfrag = *((const short8*)&Ws[(tc * 16 + c) * 32 + gq * 8]);
            acc[tc] = __builtin_amdgcn_mfma_f32_16x16x32_bf16(afrag, bfrag, acc[tc], 0, 0, 0);
        }
    }
    // epilogue: C/D layout col=lane&15, row=(lane>>4)*4+i  [m89-verified]
    int mrow = row0 + wv * 16 + gq * 4;
    if (!qmode) {
#pragma unroll
        for (int tc = 0; tc < 16; ++tc) {
            int d = tc * 16 + c;
#pragma unroll
            for (int i = 0; i < 4; ++i)
                G[(mrow + i) * EDIM + d] = acc[tc][i] + X[(mrow + i) * EDIM + d];
        }
    } else {
#pragma unroll
        for (int tc = 0; tc < 16; ++tc) {
            int d = tc * 16 + c;
            float bb = pos_b[d] + pit_b[d];
#pragma unroll
            for (int i = 0; i < 4; ++i)
                Q[(mrow + i) * EDIM + d] = acc[tc][i] + bb;
        }
    }
}

// ---------------------------------------------------------------------------
// K4: streaming assembly. out[b,f,:] = G[b,ind,:] + Q[f,:] + pitch*wp + EB[beat]
// ---------------------------------------------------------------------------
__global__ __launch_bounds__(256) void k_final(const float* __restrict__ G,
                                               const float* __restrict__ Q,
                                               const int* __restrict__ inds,
                                               const float* __restrict__ pitch,
                                               const int* __restrict__ beats,
                                               const float* __restrict__ wp,
                                               const float* __restrict__ eb,
                                               float* __restrict__ out) {
    int b = blockIdx.y;
    int f = blockIdx.x * 4 + (threadIdx.x >> 6);
    int d4 = threadIdx.x & 63;
    int ind = inds[b * FRAMES + f];
    float p = pitch[b * FRAMES + f];
    int bt = beats[b * FRAMES + f];
    f32x4 g = ((const f32x4*)G)[(b * TLEN + ind) * 64 + d4];
    f32x4 q = ((const f32x4*)Q)[f * 64 + d4];
    f32x4 w4 = ((const f32x4*)wp)[d4];
    f32x4 e4 = ((const f32x4*)eb)[bt * 64 + d4];
    f32x4 r;
#pragma unroll
    for (int i = 0; i < 4; ++i) r[i] = g[i] + q[i] + p * w4[i] + e4[i];
    ((f32x4*)out)[(b * FRAMES + f) * 64 + d4] = r;
}

extern "C" void kernel_launch(void* const* d_in, const int* in_sizes, int n_in,
                              void* d_out, int out_size, void* d_ws, size_t ws_size,
                              hipStream_t stream) {
    const float* enc   = (const float*)d_in[0];  // [16,512,256]
    const int*   ap    = (const int*)d_in[1];    // [16,8192]
    const int*   tp    = (const int*)d_in[2];    // [16,512]
    const float* pitch = (const float*)d_in[3];  // [16,8192,1]
    const int*   beats = (const int*)d_in[4];    // [16,8192,1]
    const float* wpit  = (const float*)d_in[5];  // [256,1]
    const float* bpit  = (const float*)d_in[6];  // [256]
    const float* wpos  = (const float*)d_in[7];  // [256,256]
    const float* bpos  = (const float*)d_in[8];  // [256]
    const float* ebts  = (const float*)d_in[9];  // [2,256]
    float* out = (float*)d_out;
    char* ws = (char*)d_ws;
    int*   inds  = (int*)ws;                      // 512 KB
    int*   flags = (int*)(ws + (512 << 10));      // 64 B
    float* G     = (float*)(ws + (1 << 20));      // 8 MB
    float* Q     = (float*)(ws + (9 << 20));      // 8 MB

    hipLaunchKernelGGL(k_guess,    dim3(BATCH),           dim3(1024), 0, stream, ap, tp, inds, flags);
    hipLaunchKernelGGL(k_fallback, dim3(BATCH),           dim3(64),   0, stream, ap, tp, inds, flags);
    hipLaunchKernelGGL(k_gemm,     dim3(256),             dim3(256),  0, stream, enc, wpos, bpos, bpit, G, Q);
    hipLaunchKernelGGL(k_final,    dim3(FRAMES / 4, BATCH), dim3(256), 0, stream, G, Q, inds, pitch, beats, wpit, ebts, out);
}

// Round 2
// 50.346 us; speedup vs baseline: 1.2881x; 1.2881x over previous
//
#include <hip/hip_runtime.h>
#include <hip/hip_bf16.h>

#define BATCH 16
#define FRAMES 8192
#define TLEN 512
#define EDIM 256
#define SP 56  // LDS row stride in shorts (112B): 16B-aligned, 2-way max bank aliasing

typedef __attribute__((ext_vector_type(8))) short short8;
typedef __attribute__((ext_vector_type(4))) float f32x4;

__device__ __forceinline__ unsigned short f2bf(float f) {
    unsigned u = __float_as_uint(f);
    u = (u + 0x7fffu + ((u >> 16) & 1u)) >> 16;
    return (unsigned short)u;
}

// ---------------------------------------------------------------------------
// k_prep: blocks 0..127   G[row][d] = enc[row][d] + sum_e enc[row][e]*W[d][e]
//         blocks 128..255 Q[f][d]   = sum_e PE[f][e]*W[d][e] + pos_b[d]+pit_b[d]
//         blocks 256..271 aligner-index scan (guess + verify + serial fallback)
// GEMM: 64 rows/block, 512 thr (8 waves: 4 row-groups x 2 col-halves),
// bf16 MFMA 16x16x32, padded-stride LDS tiles.
// ---------------------------------------------------------------------------
__global__ __launch_bounds__(512) void k_prep(const float* __restrict__ X,
                                              const float* __restrict__ W,
                                              const float* __restrict__ pos_b,
                                              const float* __restrict__ pit_b,
                                              const int* __restrict__ ap,
                                              const int* __restrict__ tp,
                                              float* __restrict__ G,
                                              float* __restrict__ Q,
                                              int* __restrict__ inds) {
    __shared__ short lds[(64 + 256) * SP];  // 35840 B
    int bid = blockIdx.x;
    int tid = threadIdx.x;

    if (bid >= 256) {
        // ---------------- aligner scan path ----------------
        int b = bid - 256;
        int* tps = (int*)lds;          // 512 ints
        int* wsum = tps + TLEN;        // 8 ints
        int* okp = wsum + 8;
        const int* apb = ap + b * FRAMES;
        tps[tid] = tp[b * TLEN + tid];
        if (tid == 0) *okp = 1;
        int j0 = tid * 16;
        int4 v0 = ((const int4*)apb)[tid * 4];
        int4 v1 = ((const int4*)apb)[tid * 4 + 1];
        int4 v2 = ((const int4*)apb)[tid * 4 + 2];
        int4 v3 = ((const int4*)apb)[tid * 4 + 3];
        int a[16] = {v0.x, v0.y, v0.z, v0.w, v1.x, v1.y, v1.z, v1.w,
                     v2.x, v2.y, v2.z, v2.w, v3.x, v3.y, v3.z, v3.w};
        int pr = (tid == 0) ? a[0] : apb[j0 - 1];
        int c = 0, p[16];
#pragma unroll
        for (int k = 0; k < 16; ++k) {
            c += ((j0 + k) > 0) && (a[k] != pr);
            p[k] = c;
            pr = a[k];
        }
        int lane = tid & 63, wv = tid >> 6;
        int sc = c;
#pragma unroll
        for (int d = 1; d < 64; d <<= 1) {
            int o = __shfl_up(sc, d);
            if (lane >= d) sc += o;
        }
        if (lane == 63) wsum[wv] = sc;
        __syncthreads();
        int wbase = 0;
        for (int w = 0; w < wv; ++w) wbase += wsum[w];
        int excl = wbase + sc - c;
        int g[16];
#pragma unroll
        for (int k = 0; k < 16; ++k) g[k] = min(excl + p[k], TLEN - 1);
        int4* ob = (int4*)(inds + b * FRAMES);
#pragma unroll
        for (int q4 = 0; q4 < 4; ++q4) {
            int4 wv4;
            wv4.x = g[q4 * 4]; wv4.y = g[q4 * 4 + 1];
            wv4.z = g[q4 * 4 + 2]; wv4.w = g[q4 * 4 + 3];
            ob[tid * 4 + q4] = wv4;
        }
        // exact verify
        int ok = 1, gp = min(excl, TLEN - 1);
#pragma unroll
        for (int k = 0; k < 16; ++k) {
            int j = j0 + k, e;
            if (j == 0) e = 0;
            else e = (a[k] == tps[gp]) ? gp : min(gp + 1, TLEN - 1);
            ok &= (g[k] == e);
            gp = g[k];
        }
        if (!ok) atomicAnd(okp, 0);
        __syncthreads();
        if (*okp == 0 && tid == 0) {  // serial exact fallback (never for this input)
            int ind = 0, cur = tps[0];
            int* o = inds + b * FRAMES;
            o[0] = 0;
            for (int j = 1; j < FRAMES; ++j) {
                int aj = apb[j];
                if (aj != cur && ind < TLEN - 1) { ind++; cur = tps[ind]; }
                o[j] = ind;
            }
        }
        return;
    }

    // ---------------- GEMM path ----------------
    int qmode = (bid >= 128);
    int row0 = (qmode ? bid - 128 : bid) * 64;
    short* Xs = lds;            // 64 x SP
    short* Ws = lds + 64 * SP;  // 256 x SP
    int lane = tid & 63, wv = tid >> 6;
    int c = lane & 15, gq = lane >> 4;
    int r0 = (wv & 3) * 16, c0 = (wv >> 2) * 128;
    int sr = tid >> 3, spart = tid & 7;  // staging decomposition
    f32x4 acc[8];
#pragma unroll
    for (int i = 0; i < 8; ++i) acc[i] = (f32x4){0.f, 0.f, 0.f, 0.f};

    const float kPE = -0.03597789207803197f;     // -ln(10000)/256
    const float INV2PI = 0.15915494309189535f;

    for (int ks = 0; ks < 8; ++ks) {
        int k0 = ks * 32;
        __syncthreads();
        {   // stage X tile [64 r][32 k] (4 elems/thread)
            unsigned long long pk;
            if (!qmode) {
                f32x4 u = *(const f32x4*)(X + (row0 + sr) * EDIM + k0 + spart * 4);
                pk = (unsigned long long)f2bf(u[0]) |
                     ((unsigned long long)f2bf(u[1]) << 16) |
                     ((unsigned long long)f2bf(u[2]) << 32) |
                     ((unsigned long long)f2bf(u[3]) << 48);
            } else {
                float fr = (float)(row0 + sr);
                int i2 = (k0 + spart * 4) >> 1;
                float s0, c0f, s1, c1f;
                {
                    float dv = __expf((float)(2 * i2) * kPE);
                    float rev = fr * dv * INV2PI;
                    rev = rev - floorf(rev);
                    s0 = __builtin_amdgcn_sinf(rev);
                    c0f = __builtin_amdgcn_cosf(rev);
                }
                {
                    float dv = __expf((float)(2 * i2 + 2) * kPE);
                    float rev = fr * dv * INV2PI;
                    rev = rev - floorf(rev);
                    s1 = __builtin_amdgcn_sinf(rev);
                    c1f = __builtin_amdgcn_cosf(rev);
                }
                pk = (unsigned long long)f2bf(s0) |
                     ((unsigned long long)f2bf(c0f) << 16) |
                     ((unsigned long long)f2bf(s1) << 32) |
                     ((unsigned long long)f2bf(c1f) << 48);
            }
            *((unsigned long long*)&Xs[sr * SP + spart * 4]) = pk;
        }
#pragma unroll
        for (int m = 0; m < 4; ++m) {  // stage W tile [256 d][32 k]
            int d = sr + 64 * m;
            f32x4 u = *(const f32x4*)(W + d * EDIM + k0 + spart * 4);
            unsigned long long pk = (unsigned long long)f2bf(u[0]) |
                                    ((unsigned long long)f2bf(u[1]) << 16) |
                                    ((unsigned long long)f2bf(u[2]) << 32) |
                                    ((unsigned long long)f2bf(u[3]) << 48);
            *((unsigned long long*)&Ws[d * SP + spart * 4]) = pk;
        }
        __syncthreads();
        short8 afrag = *((const short8*)&Xs[(r0 + c) * SP + gq * 8]);
#pragma unroll
        for (int tc = 0; tc < 8; ++tc) {
            short8 bfrag = *((const short8*)&Ws[(c0 + tc * 16 + c) * SP + gq * 8]);
            acc[tc] = __builtin_amdgcn_mfma_f32_16x16x32_bf16(afrag, bfrag, acc[tc], 0, 0, 0);
        }
    }
    // epilogue: C/D layout col=lane&15, row=(lane>>4)*4+i
    int mrow = row0 + r0 + gq * 4;
    if (!qmode) {
#pragma unroll
        for (int tc = 0; tc < 8; ++tc) {
            int d = c0 + tc * 16 + c;
#pragma unroll
            for (int i = 0; i < 4; ++i)
                G[(mrow + i) * EDIM + d] = acc[tc][i] + X[(mrow + i) * EDIM + d];
        }
    } else {
#pragma unroll
        for (int tc = 0; tc < 8; ++tc) {
            int d = c0 + tc * 16 + c;
            float bb = pos_b[d] + pit_b[d];
#pragma unroll
            for (int i = 0; i < 4; ++i)
                Q[(mrow + i) * EDIM + d] = acc[tc][i] + bb;
        }
    }
}

// ---------------------------------------------------------------------------
// k_final: per block 4 frames x 16 batches. Q/w/eb loaded once -> registers.
// out[b,f,:] = G[b,ind,:] + Q[f,:] + pitch*wp + EB[beat]
// ---------------------------------------------------------------------------
__global__ __launch_bounds__(256) void k_final(const float* __restrict__ G,
                                               const float* __restrict__ Q,
                                               const int* __restrict__ inds,
                                               const float* __restrict__ pitch,
                                               const int* __restrict__ beats,
                                               const float* __restrict__ wp,
                                               const float* __restrict__ eb,
                                               float* __restrict__ out) {
    int f = blockIdx.x * 4 + (threadIdx.x >> 6);
    int lane = threadIdx.x & 63;
    f32x4 q = ((const f32x4*)Q)[f * 64 + lane];
    f32x4 w4 = ((const f32x4*)wp)[lane];
    f32x4 e0 = ((const f32x4*)eb)[lane];
    f32x4 e1 = ((const f32x4*)eb)[64 + lane];
#pragma unroll
    for (int b = 0; b < BATCH; ++b) {
        int ind = inds[b * FRAMES + f];
        float p = pitch[b * FRAMES + f];
        int bt = beats[b * FRAMES + f];
        f32x4 g = ((const f32x4*)G)[(b * TLEN + ind) * 64 + lane];
        f32x4 e = bt ? e1 : e0;
        f32x4 r;
#pragma unroll
        for (int i = 0; i < 4; ++i) r[i] = g[i] + q[i] + p * w4[i] + e[i];
        __builtin_nontemporal_store(r, &((f32x4*)out)[(b * FRAMES + f) * 64 + lane]);
    }
}

extern "C" void kernel_launch(void* const* d_in, const int* in_sizes, int n_in,
                              void* d_out, int out_size, void* d_ws, size_t ws_size,
                              hipStream_t stream) {
    const float* enc   = (const float*)d_in[0];  // [16,512,256]
    const int*   ap    = (const int*)d_in[1];    // [16,8192]
    const int*   tp    = (const int*)d_in[2];    // [16,512]
    const float* pitch = (const float*)d_in[3];  // [16,8192,1]
    const int*   beats = (const int*)d_in[4];    // [16,8192,1]
    const float* wpit  = (const float*)d_in[5];  // [256,1]
    const float* bpit  = (const float*)d_in[6];  // [256]
    const float* wpos  = (const float*)d_in[7];  // [256,256]
    const float* bpos  = (const float*)d_in[8];  // [256]
    const float* ebts  = (const float*)d_in[9];  // [2,256]
    float* out = (float*)d_out;
    char* ws = (char*)d_ws;
    int*   inds = (int*)ws;                   // 512 KB
    float* G    = (float*)(ws + (1 << 20));   // 8 MB
    float* Q    = (float*)(ws + (9 << 20));   // 8 MB

    hipLaunchKernelGGL(k_prep, dim3(272), dim3(512), 0, stream,
                       enc, wpos, bpos, bpit, ap, tp, G, Q, inds);
    hipLaunchKernelGGL(k_final, dim3(FRAMES / 4), dim3(256), 0, stream,
                       G, Q, inds, pitch, beats, wpit, ebts, out);
}

// Round 4
// 45.790 us; speedup vs baseline: 1.4163x; 1.0995x over previous
//
#include <hip/hip_runtime.h>
#include <hip/hip_bf16.h>

#define BATCH 16
#define FRAMES 8192
#define TLEN 512
#define EDIM 256
#define SP 56  // LDS row stride in shorts (112B): 16B-aligned, 2-way bank aliasing max

typedef __attribute__((ext_vector_type(8))) short short8;
typedef __attribute__((ext_vector_type(4))) float f32x4;

__device__ __forceinline__ unsigned short f2bf(float f) {
    unsigned u = __float_as_uint(f);
    u = (u + 0x7fffu + ((u >> 16) & 1u)) >> 16;
    return (unsigned short)u;
}
__device__ __forceinline__ unsigned long long pack4(f32x4 u) {
    return (unsigned long long)f2bf(u[0]) |
           ((unsigned long long)f2bf(u[1]) << 16) |
           ((unsigned long long)f2bf(u[2]) << 32) |
           ((unsigned long long)f2bf(u[3]) << 48);
}

// ---------------------------------------------------------------------------
// k_prep: blocks 0..127   G[row][d] = sum_e enc[row][e]*(W+I)[d][e]  (= enc + enc·Wt)
//         blocks 128..255 Q[f][d]   = sum_e PE[f][e]*W[d][e] + pos_b[d]+pit_b[d]
//         blocks 256..271 aligner-index scan (guess + verify + serial fallback)
// GEMM: round-2-proven structure — 64 rows/block, 512 thr (8 waves:
// 4 row-groups x 2 col-halves), 8 K-steps of 32, single-buffered LDS.
// ---------------------------------------------------------------------------
__global__ __launch_bounds__(512) void k_prep(const float* __restrict__ X,
                                              const float* __restrict__ W,
                                              const float* __restrict__ pos_b,
                                              const float* __restrict__ pit_b,
                                              const int* __restrict__ ap,
                                              const int* __restrict__ tp,
                                              float* __restrict__ G,
                                              float* __restrict__ Q,
                                              int* __restrict__ inds) {
    __shared__ short lds[(64 + 256) * SP];  // 35840 B
    int bid = blockIdx.x;
    int tid = threadIdx.x;

    if (bid >= 256) {
        // ---------------- aligner scan path (round-2 proven) ----------------
        int b = bid - 256;
        int* tps = (int*)lds;          // 512 ints
        int* wsum = tps + TLEN;        // 8 ints
        int* okp = wsum + 8;
        const int* apb = ap + b * FRAMES;
        tps[tid] = tp[b * TLEN + tid];
        if (tid == 0) *okp = 1;
        int j0 = tid * 16;
        int4 v0 = ((const int4*)apb)[tid * 4];
        int4 v1 = ((const int4*)apb)[tid * 4 + 1];
        int4 v2 = ((const int4*)apb)[tid * 4 + 2];
        int4 v3 = ((const int4*)apb)[tid * 4 + 3];
        int a[16] = {v0.x, v0.y, v0.z, v0.w, v1.x, v1.y, v1.z, v1.w,
                     v2.x, v2.y, v2.z, v2.w, v3.x, v3.y, v3.z, v3.w};
        int pr = (tid == 0) ? a[0] : apb[j0 - 1];
        int c = 0, p[16];
#pragma unroll
        for (int k = 0; k < 16; ++k) {
            c += ((j0 + k) > 0) && (a[k] != pr);
            p[k] = c;
            pr = a[k];
        }
        int lane = tid & 63, wv = tid >> 6;
        int sc = c;
#pragma unroll
        for (int d = 1; d < 64; d <<= 1) {
            int o = __shfl_up(sc, d);
            if (lane >= d) sc += o;
        }
        if (lane == 63) wsum[wv] = sc;
        __syncthreads();
        int wbase = 0;
        for (int w = 0; w < wv; ++w) wbase += wsum[w];
        int excl = wbase + sc - c;
        int g[16];
#pragma unroll
        for (int k = 0; k < 16; ++k) g[k] = min(excl + p[k], TLEN - 1);
        int4* ob = (int4*)(inds + b * FRAMES);
#pragma unroll
        for (int q4 = 0; q4 < 4; ++q4) {
            int4 wv4;
            wv4.x = g[q4 * 4]; wv4.y = g[q4 * 4 + 1];
            wv4.z = g[q4 * 4 + 2]; wv4.w = g[q4 * 4 + 3];
            ob[tid * 4 + q4] = wv4;
        }
        int ok = 1, gp = min(excl, TLEN - 1);
#pragma unroll
        for (int k = 0; k < 16; ++k) {
            int j = j0 + k, e;
            if (j == 0) e = 0;
            else e = (a[k] == tps[gp]) ? gp : min(gp + 1, TLEN - 1);
            ok &= (g[k] == e);
            gp = g[k];
        }
        if (!ok) atomicAnd(okp, 0);
        __syncthreads();
        if (*okp == 0 && tid == 0) {  // exact serial fallback (never for this input)
            int ind = 0, cur = tps[0];
            int* o = inds + b * FRAMES;
            o[0] = 0;
            for (int j = 1; j < FRAMES; ++j) {
                int aj = apb[j];
                if (aj != cur && ind < TLEN - 1) { ind++; cur = tps[ind]; }
                o[j] = ind;
            }
        }
        return;
    }

    // ---------------- GEMM path ----------------
    int qmode = (bid >= 128);
    int row0 = (qmode ? bid - 128 : bid) * 64;
    short* Xs = lds;            // 64 x SP
    short* Ws = lds + 64 * SP;  // 256 x SP
    int lane = tid & 63, wv = tid >> 6;
    int c = lane & 15, gq = lane >> 4;
    int r0 = (wv & 3) * 16, cc0 = (wv >> 2) * 128;
    int sr = tid >> 3, spart = tid & 7;  // staging decomposition
    f32x4 acc[8];
#pragma unroll
    for (int i = 0; i < 8; ++i) acc[i] = (f32x4){0.f, 0.f, 0.f, 0.f};

    const float kPE = -0.03597789207803197f;     // -ln(10000)/256
    const float INV2PI = 0.15915494309189535f;

    for (int ks = 0; ks < 8; ++ks) {
        int k0 = ks * 32;
        __syncthreads();
        {   // stage X tile [64 r][32 k] (4 elems/thread)
            unsigned long long pk;
            if (!qmode) {
                f32x4 u = *(const f32x4*)(X + (row0 + sr) * EDIM + k0 + spart * 4);
                pk = pack4(u);
            } else {
                float fr = (float)(row0 + sr);
                int e0 = k0 + spart * 4;
                float dv0 = __expf((float)e0 * kPE);
                float dv1 = __expf((float)(e0 + 2) * kPE);
                float a0 = fr * dv0 * INV2PI; a0 -= floorf(a0);
                float a1 = fr * dv1 * INV2PI; a1 -= floorf(a1);
                f32x4 v;
                v[0] = __builtin_amdgcn_sinf(a0);
                v[1] = __builtin_amdgcn_cosf(a0);
                v[2] = __builtin_amdgcn_sinf(a1);
                v[3] = __builtin_amdgcn_cosf(a1);
                pk = pack4(v);
            }
            *((unsigned long long*)&Xs[sr * SP + spart * 4]) = pk;
        }
#pragma unroll
        for (int m = 0; m < 4; ++m) {  // stage W tile [256 d][32 k], +I for G-path
            int d = sr + 64 * m;
            f32x4 u = *(const f32x4*)(W + d * EDIM + k0 + spart * 4);
            if (!qmode) {
#pragma unroll
                for (int j = 0; j < 4; ++j)
                    if (d == k0 + spart * 4 + j) u[j] += 1.0f;
            }
            *((unsigned long long*)&Ws[d * SP + spart * 4]) = pack4(u);
        }
        __syncthreads();
        short8 af = *((const short8*)&Xs[(r0 + c) * SP + gq * 8]);
#pragma unroll
        for (int tc = 0; tc < 8; ++tc) {
            short8 bf = *((const short8*)&Ws[(cc0 + tc * 16 + c) * SP + gq * 8]);
            acc[tc] = __builtin_amdgcn_mfma_f32_16x16x32_bf16(af, bf, acc[tc], 0, 0, 0);
        }
    }
    // epilogue: C/D layout col=lane&15, row=(lane>>4)*4+i
    int mrow = row0 + r0 + gq * 4;
    if (!qmode) {
#pragma unroll
        for (int tc = 0; tc < 8; ++tc) {
            int d = cc0 + tc * 16 + c;
#pragma unroll
            for (int i = 0; i < 4; ++i)
                G[(mrow + i) * EDIM + d] = acc[tc][i];
        }
    } else {
#pragma unroll
        for (int tc = 0; tc < 8; ++tc) {
            int d = cc0 + tc * 16 + c;
            float bb = pos_b[d] + pit_b[d];
#pragma unroll
            for (int i = 0; i < 4; ++i)
                Q[(mrow + i) * EDIM + d] = acc[tc][i] + bb;
        }
    }
}

// ---------------------------------------------------------------------------
// k_final: 1024 blocks; block owns 8 frames x 16 batches; wave owns 4 batches.
// Unconditional G load (G/Q are LLC-resident). XCD-chunked bijective swizzle.
// out[b,f,:] = G[b,ind,:] + Q[f,:] + pitch*wp + EB[beat]
// ---------------------------------------------------------------------------
__global__ __launch_bounds__(256) void k_final(const float* __restrict__ G,
                                               const float* __restrict__ Q,
                                               const int* __restrict__ inds,
                                               const float* __restrict__ pitch,
                                               const int* __restrict__ beats,
                                               const float* __restrict__ wp,
                                               const float* __restrict__ eb,
                                               float* __restrict__ out) {
    // bijective XCD swizzle: 1024 blocks, 8 XCDs, 128 chunks each
    int swz = (blockIdx.x & 7) * 128 + (blockIdx.x >> 3);
    int f0 = swz * 8;
    int wv = threadIdx.x >> 6, lane = threadIdx.x & 63;
    f32x4 w4 = ((const f32x4*)wp)[lane];
    f32x4 e0 = ((const f32x4*)eb)[lane];
    f32x4 e1 = ((const f32x4*)eb)[64 + lane];
#pragma unroll
    for (int f = 0; f < 8; ++f) {
        f32x4 q = ((const f32x4*)Q)[(f0 + f) * 64 + lane];
#pragma unroll
        for (int bb = 0; bb < 4; ++bb) {
            int b = wv * 4 + bb;
            int idx = b * FRAMES + f0 + f;
            int ind = inds[idx];
            float p = pitch[idx];
            int bt = beats[idx];
            f32x4 g = ((const f32x4*)G)[(b * TLEN + ind) * 64 + lane];
            f32x4 e = bt ? e1 : e0;
            f32x4 r;
#pragma unroll
            for (int i = 0; i < 4; ++i) r[i] = g[i] + q[i] + p * w4[i] + e[i];
            __builtin_nontemporal_store(r, &((f32x4*)out)[idx * 64 + lane]);
        }
    }
}

extern "C" void kernel_launch(void* const* d_in, const int* in_sizes, int n_in,
                              void* d_out, int out_size, void* d_ws, size_t ws_size,
                              hipStream_t stream) {
    const float* enc   = (const float*)d_in[0];  // [16,512,256]
    const int*   ap    = (const int*)d_in[1];    // [16,8192]
    const int*   tp    = (const int*)d_in[2];    // [16,512]
    const float* pitch = (const float*)d_in[3];  // [16,8192,1]
    const int*   beats = (const int*)d_in[4];    // [16,8192,1]
    const float* wpit  = (const float*)d_in[5];  // [256,1]
    const float* bpit  = (const float*)d_in[6];  // [256]
    const float* wpos  = (const float*)d_in[7];  // [256,256]
    const float* bpos  = (const float*)d_in[8];  // [256]
    const float* ebts  = (const float*)d_in[9];  // [2,256]
    float* out = (float*)d_out;
    char* ws = (char*)d_ws;
    int*   inds = (int*)ws;                   // 512 KB
    float* G    = (float*)(ws + (1 << 20));   // 8 MB
    float* Q    = (float*)(ws + (9 << 20));   // 8 MB

    hipLaunchKernelGGL(k_prep, dim3(272), dim3(512), 0, stream,
                       enc, wpos, bpos, bpit, ap, tp, G, Q, inds);
    hipLaunchKernelGGL(k_final, dim3(1024), dim3(256), 0, stream,
                       G, Q, inds, pitch, beats, wpit, ebts, out);
}